// Round 1
// baseline (95.159 us; speedup 1.0000x reference)
//
#include <hip/hip_runtime.h>

// ProdLayer forward (block_size==1, single partition, accum=False):
//   element_mars[nids] = node_mars[cids].sum(axis=1)
// node_mars:    [131072, 512] f32
// element_mars: [ 65600, 512] f32 (kept for rows not targeted by nids)
// nids:         [65536]       int32 (== arange; unique scatter targets)
// cids:         [65536, 4]    int32
// out:          [ 65600, 512] f32
//
// Memory-bound: ~537 MB gather reads + 134 MB writes; roofline ~100 us.

constexpr int BATCH   = 512;
constexpr int N_PROD  = 65536;
constexpr int MAX_ELS = 65600;
constexpr int N_EDGES = 4;
constexpr int VEC     = 4;                  // float4
constexpr int LANES   = BATCH / VEC;        // 128 float4 per row
constexpr int ROWS_PER_BLOCK = 2;           // 256 threads = 2 x 128

__global__ __launch_bounds__(256) void ProdLayer_69750268887705_kernel(
    const float* __restrict__ node_mars,
    const float* __restrict__ element_mars,
    const int*   __restrict__ nids,
    const int*   __restrict__ cids,
    float*       __restrict__ out)
{
    const int tid   = threadIdx.x;
    const int rsub  = tid >> 7;             // 0/1: which row of this block (wave-uniform)
    const int lane  = tid & (LANES - 1);    // float4 column index 0..127
    const int p     = blockIdx.x * ROWS_PER_BLOCK + rsub;
    if (p >= MAX_ELS) return;

    if (p < N_PROD) {
        // gather 4 child rows, sum, scatter to nids[p]
        const int out_row = nids[p];
        const int c0 = cids[p * N_EDGES + 0];
        const int c1 = cids[p * N_EDGES + 1];
        const int c2 = cids[p * N_EDGES + 2];
        const int c3 = cids[p * N_EDGES + 3];
        const float4* r0 = (const float4*)(node_mars + (size_t)c0 * BATCH);
        const float4* r1 = (const float4*)(node_mars + (size_t)c1 * BATCH);
        const float4* r2 = (const float4*)(node_mars + (size_t)c2 * BATCH);
        const float4* r3 = (const float4*)(node_mars + (size_t)c3 * BATCH);
        float4 a = r0[lane];
        float4 b = r1[lane];
        float4 c = r2[lane];
        float4 d = r3[lane];
        float4 s;
        s.x = (a.x + b.x) + (c.x + d.x);
        s.y = (a.y + b.y) + (c.y + d.y);
        s.z = (a.z + b.z) + (c.z + d.z);
        s.w = (a.w + b.w) + (c.w + d.w);
        ((float4*)(out + (size_t)out_row * BATCH))[lane] = s;
    } else {
        // rows never targeted by the scatter (nids == arange(N_PROD)):
        // keep original element_mars values (input is zeros, but copy to be safe)
        ((float4*)(out + (size_t)p * BATCH))[lane] =
            ((const float4*)(element_mars + (size_t)p * BATCH))[lane];
    }
}

extern "C" void kernel_launch(void* const* d_in, const int* in_sizes, int n_in,
                              void* d_out, int out_size, void* d_ws, size_t ws_size,
                              hipStream_t stream) {
    const float* node_mars    = (const float*)d_in[0];
    const float* element_mars = (const float*)d_in[1];
    const int*   nids         = (const int*)d_in[2];
    const int*   cids         = (const int*)d_in[3];
    float*       out          = (float*)d_out;

    const int nBlocks = (MAX_ELS + ROWS_PER_BLOCK - 1) / ROWS_PER_BLOCK;  // 32800
    ProdLayer_69750268887705_kernel<<<nBlocks, 256, 0, stream>>>(
        node_mars, element_mars, nids, cids, out);
}